// Round 13
// baseline (156.406 us; speedup 1.0000x reference)
//
#include <hip/hip_runtime.h>

// PWC-Net correlation (md=4, 81 disps) + leaky_relu(0.1), mean over C=256.
// B=8 C=256 H=96 W=128, f32 in/out.
//
// R13: MFMA engine. out[w, dx] = sum_c x1[w,c] * x2[w+dx-4,c] is a banded
// matmul: per w-tile of 16, TWO mfma_f32_16x16x32_f16 (N-tiles at wt-4 and
// wt+12) cover all 9 dx per 32-channel K-slice. 8 K-slices, 8 MFMA/wave/
// slice. A(x1) and B(x2) staged with the IDENTICAL [px][chpair] layout so
// any hardware k-permutation cancels (A/B symmetric); C/D layout per guide
// (col=lane&15, row=(lane>>4)*4+reg, HW-verified).
// Block = 3 waves (192 thr), wave = one dy of 3-dy group; grid =
// 8(b==XCD) x 96(h) x 6(dg*2+whalf). LDS px-stride 20 u32 (coprime banks
// -> b128 reads AND writes at floor, no XOR swizzle needed).
// Barriers 64 -> ~19. Epilogue: acc -> LDS scatter -> coalesced f32x4.
// Lessons: spills fatal (sentinel WRITE_SIZE >> 31MB); keep staging live
// ranges short; x1 via LDS; stage;sync;compute;sync (no phase reordering).

#define B_ 8
#define C_ 256
#define H_ 96
#define W_ 128
#define HW (H_ * W_)             // 12288 = channel stride (floats)
#define NSL 8                    // K-slices of 32 channels
#define SLSTRIDE (32u * HW)      // floats per K-slice step

#define X1OFF 0                  // 64 px * 20 u32
#define X2OFF (64 * 20)          // 1280
#define X2ROW (84 * 20)          // 1680 u32 per staged x2 row (84 px)
#define SMSZ  (X2OFF + 3 * X2ROW)// 6320 u32 = 25.3 KB
#define NTHR 192
#define NTASK 316                // 64 x1 + 252 x2 staging tasks

typedef __fp16 h2_t  __attribute__((ext_vector_type(2)));
typedef __fp16 f16x8 __attribute__((ext_vector_type(8)));
typedef float  f32x4 __attribute__((ext_vector_type(4)));
union H2U { unsigned int u; h2_t h; };

__device__ __forceinline__ unsigned int packh2(float a, float b) {
    H2U x; x.h = __builtin_amdgcn_cvt_pkrtz(a, b); return x.u;
}

__global__ __attribute__((amdgpu_flat_work_group_size(NTHR, NTHR)))
void corr_kernel(const float* __restrict__ x1, const float* __restrict__ x2,
                 float* __restrict__ out)
{
    __shared__ __align__(16) unsigned int smem[SMSZ];

    const int b   = blockIdx.x;        // batch == XCD (x fastest)
    const int h   = blockIdx.y;
    const int z   = blockIdx.z;        // 0..5
    const int dg  = z >> 1;            // dy group
    const int w0  = (z & 1) * 64;      // w half
    const int tid = threadIdx.x;
    const int wid = tid >> 6;          // wave = dy-in-group (0..2)
    const int lane = tid & 63;
    const int l15 = lane & 15, g = lane >> 4;

    // ---------------- staging descriptors: 2 rounds x 192 threads ----------
    // T<64: x1. chgrp=T&3 (8ch), w4=T>>2 (4px). px_local=4*w4.
    // 64<=T<316: x2. U=T-64: chgrp=U&3, rest=U>>2, g4=rest%21 (4px of 84),
    //   r=rest/21 (row 0..2). global row h+3dg+r-4, w = w0-8+4*g4.
    // LDS u32 idx: [X1OFF|X2OFF+r*X2ROW] + px_local*20 + chgrp*4 (+j*20/px).
    unsigned soff[2]; int sbase[2]; bool val_[2], isx2_[2];
    #pragma unroll
    for (int i = 0; i < 2; ++i) {
        const int T = tid + NTHR * i;
        bool val = false, isx2 = false; unsigned off = 0; int sb = 0;
        if (T < 64) {
            const int chgrp = T & 3, w4 = T >> 2;
            off = (unsigned)(b * C_ + 8 * chgrp) * HW
                + (unsigned)(h * W_ + w0 + 4 * w4);
            sb  = X1OFF + (4 * w4) * 20 + chgrp * 4;
            val = true;
        } else if (T < NTASK) {
            const int U = T - 64;
            const int chgrp = U & 3, rest = U >> 2;
            const int g4 = rest % 21, r = rest / 21;
            const int h2 = h + 3 * dg + r - 4;
            const int wg = w0 - 8 + 4 * g4;
            val  = (h2 >= 0) && (h2 < H_) && (wg >= 0) && (wg <= W_ - 4);
            off = (unsigned)(b * C_ + 8 * chgrp) * HW
                + (unsigned)((val ? h2 : 0) * W_ + (val ? wg : 0));
            sb  = X2OFF + r * X2ROW + (4 * g4) * 20 + chgrp * 4;
            isx2 = true;
        }
        soff[i] = off; sbase[i] = sb; val_[i] = val; isx2_[i] = isx2;
    }

    // zero-fill slots of invalid x2 tasks ONCE (never staged later)
    #pragma unroll
    for (int i = 0; i < 2; ++i) {
        const int T = tid + NTHR * i;
        if (T < NTASK && isx2_[i] && !val_[i]) {
            const uint4 zz = {0u, 0u, 0u, 0u};
            #pragma unroll
            for (int j = 0; j < 4; ++j)
                *reinterpret_cast<uint4*>(&smem[sbase[i] + j * 20]) = zz;
        }
    }

    // ---------------- accumulators ----------------
    f32x4 accL[4], accH[4];
    #pragma unroll
    for (int t = 0; t < 4; ++t) {
        accL[t] = (f32x4){0.f, 0.f, 0.f, 0.f};
        accH[t] = (f32x4){0.f, 0.f, 0.f, 0.f};
    }

    const int abase = X1OFF + l15 * 20 + g * 4;
    const int bbase = X2OFF + wid * X2ROW + (4 + l15) * 20 + g * 4;

    // ---------------- K-slice loop: stage; sync; mfma; sync ----------------
    #pragma unroll 1
    for (int ss = 0; ss < NSL; ++ss) {
        #pragma unroll
        for (int i = 0; i < 2; ++i) {
            if (val_[i]) {
                const float* p = (isx2_[i] ? x2 : x1) + soff[i]
                               + (unsigned)ss * SLSTRIDE;
                const float4 f0 = *reinterpret_cast<const float4*>(p);
                const float4 f1 = *reinterpret_cast<const float4*>(p + HW);
                const float4 f2 = *reinterpret_cast<const float4*>(p + 2 * HW);
                const float4 f3 = *reinterpret_cast<const float4*>(p + 3 * HW);
                const float4 f4 = *reinterpret_cast<const float4*>(p + 4 * HW);
                const float4 f5 = *reinterpret_cast<const float4*>(p + 5 * HW);
                const float4 f6 = *reinterpret_cast<const float4*>(p + 6 * HW);
                const float4 f7 = *reinterpret_cast<const float4*>(p + 7 * HW);
                uint4 wv;
                wv.x = packh2(f0.x, f1.x); wv.y = packh2(f2.x, f3.x);
                wv.z = packh2(f4.x, f5.x); wv.w = packh2(f6.x, f7.x);
                *reinterpret_cast<uint4*>(&smem[sbase[i] + 0 * 20]) = wv;
                wv.x = packh2(f0.y, f1.y); wv.y = packh2(f2.y, f3.y);
                wv.z = packh2(f4.y, f5.y); wv.w = packh2(f6.y, f7.y);
                *reinterpret_cast<uint4*>(&smem[sbase[i] + 1 * 20]) = wv;
                wv.x = packh2(f0.z, f1.z); wv.y = packh2(f2.z, f3.z);
                wv.z = packh2(f4.z, f5.z); wv.w = packh2(f6.z, f7.z);
                *reinterpret_cast<uint4*>(&smem[sbase[i] + 2 * 20]) = wv;
                wv.x = packh2(f0.w, f1.w); wv.y = packh2(f2.w, f3.w);
                wv.z = packh2(f4.w, f5.w); wv.w = packh2(f6.w, f7.w);
                *reinterpret_cast<uint4*>(&smem[sbase[i] + 3 * 20]) = wv;
            }
        }
        __syncthreads();

        f16x8 Bc = *reinterpret_cast<const f16x8*>(&smem[bbase]);
        #pragma unroll
        for (int t = 0; t < 4; ++t) {
            const f16x8 Av = *reinterpret_cast<const f16x8*>(&smem[abase + t * 320]);
            const f16x8 Bn = *reinterpret_cast<const f16x8*>(&smem[bbase + (t + 1) * 320]);
            accL[t] = __builtin_amdgcn_mfma_f32_16x16x32_f16(Av, Bc, accL[t], 0, 0, 0);
            accH[t] = __builtin_amdgcn_mfma_f32_16x16x32_f16(Av, Bn, accH[t], 0, 0, 0);
            Bc = Bn;
        }
        __syncthreads();
    }

    // ---------------- epilogue: scatter acc -> LDS, coalesced stores -------
    // D layout: col n = lane&15, row m = (lane>>4)*4 + reg.
    // tile L (base wt-4):  dx = n - m      (0..8 valid)
    // tile H (base wt+12): dx = 16 + n - m (<=8 valid; >=1 always)
    float* const smf = reinterpret_cast<float*>(smem);
    const int ebase = wid * 576;                 // 9 dx * 64 w per wave
    #pragma unroll
    for (int t = 0; t < 4; ++t) {
        #pragma unroll
        for (int reg = 0; reg < 4; ++reg) {
            const int m = 4 * g + reg;
            const int dL = l15 - m;
            if (dL >= 0 && dL <= 8)
                smf[ebase + dL * 64 + 16 * t + m] = accL[t][reg];
            const int dH = 16 + l15 - m;
            if (dH <= 8)
                smf[ebase + dH * 64 + 16 * t + m] = accH[t][reg];
        }
    }
    __syncthreads();

    const float inv = 1.0f / 256.0f;
    const int dy = 3 * dg + wid;
    float* ob = out + ((size_t)(b * 81 + dy * 9) * H_ + h) * W_ + w0;
    #pragma unroll
    for (int r2 = 0; r2 < 3; ++r2) {
        const int u = lane + 64 * r2;
        if (u < 144) {
            const int dxr = u >> 4, w4r = u & 15;
            const float4 v = *reinterpret_cast<const float4*>(
                &smf[ebase + dxr * 64 + 4 * w4r]);
            float4 o; float s;
            s = v.x * inv; o.x = s >= 0.f ? s : 0.1f * s;
            s = v.y * inv; o.y = s >= 0.f ? s : 0.1f * s;
            s = v.z * inv; o.z = s >= 0.f ? s : 0.1f * s;
            s = v.w * inv; o.w = s >= 0.f ? s : 0.1f * s;
            *reinterpret_cast<float4*>(&ob[(size_t)dxr * HW + 4 * w4r]) = o;
        }
    }
}

extern "C" void kernel_launch(void* const* d_in, const int* in_sizes, int n_in,
                              void* d_out, int out_size, void* d_ws, size_t ws_size,
                              hipStream_t stream) {
    const float* x1 = (const float*)d_in[0];
    const float* x2 = (const float*)d_in[1];
    float* out = (float*)d_out;
    corr_kernel<<<dim3(B_, H_, 6), dim3(NTHR), 0, stream>>>(x1, x2, out);
}

// Round 14
// 97.500 us; speedup vs baseline: 1.6042x; 1.6042x over previous
//
#include <hip/hip_runtime.h>

// PWC-Net correlation (md=4, 81 disps) + leaky_relu(0.1), mean over C=256.
// B=8 C=256 H=96 W=128, f32 in/out.
//
// R14: ONE-WAVE WORKGROUPS -- no s_barrier at all (workgroup == wavefront
// => backend elides barriers; __syncthreads degenerates to waitcnt).
// Each wave = one (h-tile, dy): stages its own 2 x1 rows + 2 x2 rows and
// computes 2x128px x 9dx. Grid 8(b==XCD) x 9(dy) x 48(h0): all 9 dy of an
// h-tile co-resident on one XCD -> x1/x2 rows L2-hit despite 9x restage.
// Staging = R12's wide tasks (8 float4 loads -> 16 packh2 -> 4 ds_write
// _b128), exactly 2 tasks/lane/chunk. Compute = R12 verbatim (f16 dot2,
// conflict-free XOR swizzle, b128 reads).
// Lessons: R5/R6/R11 spills fatal (sentinel WRITE_SIZE >> 31MB, ~84 VGPR
// budget); R8 x1 via L1 thrashes; R9/R10 multi-wave reordering loses to
// removing the coupling (this); R13 MFMA starves (stage >> compute).

#define B_ 8
#define C_ 256
#define H_ 96
#define W_ 128
#define TH 2
#define CC 8
#define NCH (C_ / CC)            // 32 chunks
#define HW (H_ * W_)
#define CHSTRIDE (CC * HW)       // floats, fits u32
#define S2SZ (TH * 544)          // 1088 u32 (2 staged x2 rows)
#define S1SZ (TH * 512)          // 1024 u32
#define SMSZ (S2SZ + S1SZ)       // 2112 u32 = 8.45 KB
#define NTHR 64

typedef __fp16 h2_t __attribute__((ext_vector_type(2)));
union H2U { unsigned int u; h2_t h; };

__device__ __forceinline__ h2_t u_as_h2(unsigned int u) { H2U x; x.u = u; return x.h; }

__device__ __forceinline__ unsigned int packh2(float a, float b) {
    H2U x; x.h = __builtin_amdgcn_cvt_pkrtz(a, b); return x.u;
}

#if __has_builtin(__builtin_amdgcn_fdot2)
__device__ __forceinline__ float dot2(unsigned int a, unsigned int b, float c) {
    return __builtin_amdgcn_fdot2(u_as_h2(a), u_as_h2(b), c, false);
}
#else
__device__ __forceinline__ float dot2(unsigned int a, unsigned int b, float c) {
    h2_t ha = u_as_h2(a), hb = u_as_h2(b);
    return c + (float)ha[0] * (float)hb[0] + (float)ha[1] * (float)hb[1];
}
#endif

__global__ __attribute__((amdgpu_flat_work_group_size(NTHR, NTHR)))
void corr_kernel(const float* __restrict__ x1, const float* __restrict__ x2,
                 float* __restrict__ out)
{
    // s2 (2 rows x 544) at [0, S2SZ), s1 (2 rows x 512) at [S2SZ, SMSZ)
    __shared__ __align__(16) unsigned int smem[SMSZ];

    const int b   = blockIdx.x;       // batch == XCD (x fastest => round-robin)
    const int dy  = blockIdx.y;       // 0..8
    const int h0  = blockIdx.z * TH;
    const int lane = threadIdx.x;     // block == one wave
    const int hr  = lane >> 5;        // 0..1
    const int wq  = lane & 31;        // 32 groups of 4 w pixels

    // ---------------- staging descriptors: 2 wide tasks per lane -----------
    // Task A (x1): rx=lane>>5, w4=lane&31. 4 px x 8 ch.
    // Task B (x2): r=lane>>5, g=(lane&31)+1 (g=1..32; pads g=0/33 stay 0).
    // LDS u32 idx for slot s, ch-pair cp, row r:
    //   [S2SZ +] r*544(512) + (s>>3)*32 + (((s&7)^((s>>3)&7)^r)<<2) + cp
    // One b128 write covers cp0..3 of one swizzled slot: c + ((k^X)<<2).
    const int rx = hr, w4 = wq;
    const unsigned off1 =
        (unsigned)(b * C_) * HW + (unsigned)((h0 + rx) * W_ + 4 * w4);
    const int c1 = S2SZ + rx * 512 + (w4 >> 1) * 32;
    const int X1 = (4 * (w4 & 1)) ^ ((w4 >> 1) & 7) ^ rx;

    const int r2 = hr, g = wq + 1;
    const int h2 = h0 + dy + r2 - 4;
    const bool val2 = (h2 >= 0) && (h2 < H_);
    const unsigned off2 =
        (unsigned)(b * C_) * HW + (unsigned)((val2 ? h2 : 0) * W_ + 4 * g - 4);
    const int c2 = r2 * 544 + (g >> 1) * 32;
    const int X2 = (4 * (g & 1)) ^ ((g >> 1) & 7) ^ r2;

    // ---------------- compute setup (R12 verbatim, row = hr) ---------------
    const int base1 = S2SZ + hr * 512 + (wq >> 1) * 32;
    const int S1X   = (4 * (wq & 1)) ^ ((wq >> 1) & 7) ^ hr;

    int a2p[6];                            // 12 chunk-invariant addrs, 2x16b
    #pragma unroll
    for (int t = 0; t < 12; t += 2) {
        const int s0 = 4 * wq + t, s1 = s0 + 1;
        const int A0 = hr * 544 + (s0 >> 3) * 32
                     + (((s0 & 7) ^ ((s0 >> 3) & 7) ^ hr) << 2);
        const int A1 = hr * 544 + (s1 >> 3) * 32
                     + (((s1 & 7) ^ ((s1 >> 3) & 7) ^ hr) << 2);
        a2p[t >> 1] = A0 | (A1 << 16);
    }

    float acc[4][9];
    #pragma unroll
    for (int p = 0; p < 4; ++p)
        #pragma unroll
        for (int d = 0; d < 9; ++d) acc[p][d] = 0.f;

    // zero pad slots of s2 (g=0/33 quads, invalid rows; never staged)
    #pragma unroll
    for (int i = 0; i < S2SZ / NTHR; ++i) smem[lane + i * NTHR] = 0u;
    __syncthreads();

    // ---------------- chunk loop: stage; (waitcnt); compute ----------------
    #pragma unroll 1
    for (int cc = 0; cc < NCH; ++cc) {
        const unsigned co = (unsigned)cc * (unsigned)CHSTRIDE;
        {   // x1 task (always valid)
            const float* p = x1 + off1 + co;
            const float4 f0 = *reinterpret_cast<const float4*>(p);
            const float4 f1 = *reinterpret_cast<const float4*>(p + HW);
            const float4 f2 = *reinterpret_cast<const float4*>(p + 2 * HW);
            const float4 f3 = *reinterpret_cast<const float4*>(p + 3 * HW);
            const float4 f4 = *reinterpret_cast<const float4*>(p + 4 * HW);
            const float4 f5 = *reinterpret_cast<const float4*>(p + 5 * HW);
            const float4 f6 = *reinterpret_cast<const float4*>(p + 6 * HW);
            const float4 f7 = *reinterpret_cast<const float4*>(p + 7 * HW);
            uint4 wv;
            wv.x = packh2(f0.x, f1.x); wv.y = packh2(f2.x, f3.x);
            wv.z = packh2(f4.x, f5.x); wv.w = packh2(f6.x, f7.x);
            *reinterpret_cast<uint4*>(&smem[c1 + ((0 ^ X1) << 2)]) = wv;
            wv.x = packh2(f0.y, f1.y); wv.y = packh2(f2.y, f3.y);
            wv.z = packh2(f4.y, f5.y); wv.w = packh2(f6.y, f7.y);
            *reinterpret_cast<uint4*>(&smem[c1 + ((1 ^ X1) << 2)]) = wv;
            wv.x = packh2(f0.z, f1.z); wv.y = packh2(f2.z, f3.z);
            wv.z = packh2(f4.z, f5.z); wv.w = packh2(f6.z, f7.z);
            *reinterpret_cast<uint4*>(&smem[c1 + ((2 ^ X1) << 2)]) = wv;
            wv.x = packh2(f0.w, f1.w); wv.y = packh2(f2.w, f3.w);
            wv.z = packh2(f4.w, f5.w); wv.w = packh2(f6.w, f7.w);
            *reinterpret_cast<uint4*>(&smem[c1 + ((3 ^ X1) << 2)]) = wv;
        }
        if (val2) {   // x2 task
            const float* p = x2 + off2 + co;
            const float4 f0 = *reinterpret_cast<const float4*>(p);
            const float4 f1 = *reinterpret_cast<const float4*>(p + HW);
            const float4 f2 = *reinterpret_cast<const float4*>(p + 2 * HW);
            const float4 f3 = *reinterpret_cast<const float4*>(p + 3 * HW);
            const float4 f4 = *reinterpret_cast<const float4*>(p + 4 * HW);
            const float4 f5 = *reinterpret_cast<const float4*>(p + 5 * HW);
            const float4 f6 = *reinterpret_cast<const float4*>(p + 6 * HW);
            const float4 f7 = *reinterpret_cast<const float4*>(p + 7 * HW);
            uint4 wv;
            wv.x = packh2(f0.x, f1.x); wv.y = packh2(f2.x, f3.x);
            wv.z = packh2(f4.x, f5.x); wv.w = packh2(f6.x, f7.x);
            *reinterpret_cast<uint4*>(&smem[c2 + ((0 ^ X2) << 2)]) = wv;
            wv.x = packh2(f0.y, f1.y); wv.y = packh2(f2.y, f3.y);
            wv.z = packh2(f4.y, f5.y); wv.w = packh2(f6.y, f7.y);
            *reinterpret_cast<uint4*>(&smem[c2 + ((1 ^ X2) << 2)]) = wv;
            wv.x = packh2(f0.z, f1.z); wv.y = packh2(f2.z, f3.z);
            wv.z = packh2(f4.z, f5.z); wv.w = packh2(f6.z, f7.z);
            *reinterpret_cast<uint4*>(&smem[c2 + ((2 ^ X2) << 2)]) = wv;
            wv.x = packh2(f0.w, f1.w); wv.y = packh2(f2.w, f3.w);
            wv.z = packh2(f4.w, f5.w); wv.w = packh2(f6.w, f7.w);
            *reinterpret_cast<uint4*>(&smem[c2 + ((3 ^ X2) << 2)]) = wv;
        }
        __syncthreads();              // 1-wave block: waitcnt only, no barrier

        uint4 x1v[4];
        #pragma unroll
        for (int p = 0; p < 4; ++p)
            x1v[p] = *reinterpret_cast<const uint4*>(&smem[base1 + ((p ^ S1X) << 2)]);
        #pragma unroll
        for (int t = 0; t < 12; ++t) {
            const int ad = (t & 1) ? (a2p[t >> 1] >> 16) : (a2p[t >> 1] & 0xffff);
            const uint4 x2v = *reinterpret_cast<const uint4*>(&smem[ad]);
            #pragma unroll
            for (int p = 0; p < 4; ++p) {
                const int dxx = t - p;          // compile-time after unroll
                if (dxx >= 0 && dxx <= 8) {
                    float a = acc[p][dxx];
                    a = dot2(x1v[p].x, x2v.x, a);
                    a = dot2(x1v[p].y, x2v.y, a);
                    a = dot2(x1v[p].z, x2v.z, a);
                    a = dot2(x1v[p].w, x2v.w, a);
                    acc[p][dxx] = a;
                }
            }
        }
        __syncthreads();              // reads done before next stage (waitcnt)
    }

    // ---------------- epilogue: mean + leaky_relu + coalesced f32x4 writes -
    const float inv = 1.0f / 256.0f;
    float* ob = out + (((size_t)(b * 81 + dy * 9)) * H_ + (h0 + hr)) * W_ + wq * 4;
    #pragma unroll
    for (int dxx = 0; dxx < 9; ++dxx) {
        float4 o;
        float v;
        v = acc[0][dxx] * inv; o.x = v >= 0.f ? v : 0.1f * v;
        v = acc[1][dxx] * inv; o.y = v >= 0.f ? v : 0.1f * v;
        v = acc[2][dxx] * inv; o.z = v >= 0.f ? v : 0.1f * v;
        v = acc[3][dxx] * inv; o.w = v >= 0.f ? v : 0.1f * v;
        *reinterpret_cast<float4*>(ob + (size_t)dxx * HW) = o;
    }
}

extern "C" void kernel_launch(void* const* d_in, const int* in_sizes, int n_in,
                              void* d_out, int out_size, void* d_ws, size_t ws_size,
                              hipStream_t stream) {
    const float* x1 = (const float*)d_in[0];
    const float* x2 = (const float*)d_in[1];
    float* out = (float*)d_out;
    corr_kernel<<<dim3(B_, 9, H_ / TH), dim3(NTHR), 0, stream>>>(x1, x2, out);
}

// Round 15
// 84.186 us; speedup vs baseline: 1.8579x; 1.1581x over previous
//
#include <hip/hip_runtime.h>

// PWC-Net correlation (md=4, 81 disps) + leaky_relu(0.1), mean over C=256.
// B=8 C=256 H=96 W=128, f32 in/out.
//
// R15 = R12 (champion, 82us) with CC=16: each phase stages TWO 8-channel
// planes (same wide task per thread, run twice: plane1 at +8*HW globally,
// +3200 u32 in LDS) then computes both -> barriers 64 -> 32, double-length
// compute section per vmcnt drain.
// Wide staging task (R12): 8 coalesced float4 loads -> 16 packh2 ->
// 4 ds_write_b128; exactly 192 tasks = 1/thread/plane, no masks.
// Block = 3 waves (192 thr), wave = one dy of 3-dy group; grid =
// 8(b==XCD) x 48(h-tiles) x 3(dy-groups) = 1152 blocks.
// Compute: f16 dot2, conflict-free XOR swizzle, b128 reads (R12 verbatim).
// Lessons: spills fatal (sentinel WRITE_SIZE >> 31MB); staging live ranges
// stay short (R12's 52 VGPR proves compiler fine-schedules them); x1 via
// LDS (R8); barrier-free 1-wave loses to shared staging (R14); MFMA
// starves at this stage:compute ratio (R13).

#define B_ 8
#define C_ 256
#define H_ 96
#define W_ 128
#define TH 2
#define CC 16
#define NCH (C_ / CC)            // 16 chunks
#define HW (H_ * W_)
#define CHSTRIDE (CC * HW)       // floats, fits u32
#define S2SZ (4 * 544)           // 2176 u32 (4 staged x2 rows) per plane
#define S1SZ (TH * 512)          // 1024 u32 per plane
#define PL (S2SZ + S1SZ)         // 3200 u32 = 12.8 KB per plane
#define SMSZ (2 * PL)            // 25.6 KB
#define NTHR 192

typedef __fp16 h2_t __attribute__((ext_vector_type(2)));
union H2U { unsigned int u; h2_t h; };

__device__ __forceinline__ h2_t u_as_h2(unsigned int u) { H2U x; x.u = u; return x.h; }

__device__ __forceinline__ unsigned int packh2(float a, float b) {
    H2U x; x.h = __builtin_amdgcn_cvt_pkrtz(a, b); return x.u;
}

#if __has_builtin(__builtin_amdgcn_fdot2)
__device__ __forceinline__ float dot2(unsigned int a, unsigned int b, float c) {
    return __builtin_amdgcn_fdot2(u_as_h2(a), u_as_h2(b), c, false);
}
#else
__device__ __forceinline__ float dot2(unsigned int a, unsigned int b, float c) {
    h2_t ha = u_as_h2(a), hb = u_as_h2(b);
    return c + (float)ha[0] * (float)hb[0] + (float)ha[1] * (float)hb[1];
}
#endif

__global__ __attribute__((amdgpu_flat_work_group_size(NTHR, NTHR)))
void corr_kernel(const float* __restrict__ x1, const float* __restrict__ x2,
                 float* __restrict__ out)
{
    // per plane: s2 (4 rows x 544) at [0,S2SZ), s1 (2 rows x 512) after
    __shared__ __align__(16) unsigned int smem[SMSZ];

    const int b   = blockIdx.x;       // batch == XCD (x fastest => round-robin)
    const int h0  = blockIdx.y * TH;
    const int dg  = blockIdx.z;       // dy = 3*dg + wid
    const int tid = threadIdx.x;
    const int wid = tid >> 6;         // 0..2
    const int lane = tid & 63;
    const int hr  = lane >> 5;        // 0..1
    const int wq  = lane & 31;        // 32 groups of 4 w pixels

    // ---------------- staging descriptor: ONE wide task per thread/plane ---
    // tid<64: x1. rx=tid>>5, w4=tid&31. 4 px x 8 ch of the plane.
    // tid>=64: x2. v=tid-64: r=v>>5 (0..3), g=(v&31)+1 (g=1..32; pad quads
    //   g=0/33 pre-zeroed, never staged).
    // LDS u32 idx for slot s, ch-pair cp, row r (within a plane):
    //   [S2SZ +] r*544(512) + (s>>3)*32 + (((s&7)^((s>>3)&7)^(r&7))<<2) + cp
    // One b128 write covers cp0..3 of one swizzled slot: c + ((k^X)<<2).
    unsigned off; int c, X; bool val, src2;
    if (tid < 64) {
        const int rx = tid >> 5, w4 = tid & 31;
        off = (unsigned)(b * C_) * HW + (unsigned)((h0 + rx) * W_ + 4 * w4);
        c = S2SZ + rx * 512 + (w4 >> 1) * 32;
        X = (4 * (w4 & 1)) ^ ((w4 >> 1) & 7) ^ rx;
        val = true; src2 = false;
    } else {
        const int v = tid - 64;
        const int r = v >> 5, g = (v & 31) + 1;
        const int h2 = h0 + 3 * dg + r - 4;
        val = (h2 >= 0) && (h2 < H_);
        off = (unsigned)(b * C_) * HW
            + (unsigned)((val ? h2 : 0) * W_ + 4 * g - 4);
        c = r * 544 + (g >> 1) * 32;
        X = (4 * (g & 1)) ^ ((g >> 1) & 7) ^ (r & 7);
        src2 = true;
    }
    const float* const sbase = src2 ? x2 : x1;

    auto STAGE = [&](int cc, int j) {       // j = plane (literal at call site)
        if (val) {
            const float* p = sbase + off
                           + (unsigned)cc * (unsigned)CHSTRIDE
                           + (unsigned)j * (8u * HW);
            const int cj = c + j * PL;
            const float4 f0 = *reinterpret_cast<const float4*>(p);
            const float4 f1 = *reinterpret_cast<const float4*>(p + HW);
            const float4 f2 = *reinterpret_cast<const float4*>(p + 2 * HW);
            const float4 f3 = *reinterpret_cast<const float4*>(p + 3 * HW);
            const float4 f4 = *reinterpret_cast<const float4*>(p + 4 * HW);
            const float4 f5 = *reinterpret_cast<const float4*>(p + 5 * HW);
            const float4 f6 = *reinterpret_cast<const float4*>(p + 6 * HW);
            const float4 f7 = *reinterpret_cast<const float4*>(p + 7 * HW);
            uint4 wv;
            wv.x = packh2(f0.x, f1.x); wv.y = packh2(f2.x, f3.x);
            wv.z = packh2(f4.x, f5.x); wv.w = packh2(f6.x, f7.x);
            *reinterpret_cast<uint4*>(&smem[cj + ((0 ^ X) << 2)]) = wv;
            wv.x = packh2(f0.y, f1.y); wv.y = packh2(f2.y, f3.y);
            wv.z = packh2(f4.y, f5.y); wv.w = packh2(f6.y, f7.y);
            *reinterpret_cast<uint4*>(&smem[cj + ((1 ^ X) << 2)]) = wv;
            wv.x = packh2(f0.z, f1.z); wv.y = packh2(f2.z, f3.z);
            wv.z = packh2(f4.z, f5.z); wv.w = packh2(f6.z, f7.z);
            *reinterpret_cast<uint4*>(&smem[cj + ((2 ^ X) << 2)]) = wv;
            wv.x = packh2(f0.w, f1.w); wv.y = packh2(f2.w, f3.w);
            wv.z = packh2(f4.w, f5.w); wv.w = packh2(f6.w, f7.w);
            *reinterpret_cast<uint4*>(&smem[cj + ((3 ^ X) << 2)]) = wv;
        }
    };

    // ---------------- compute setup (R12 verbatim) ----------------
    const int base1 = S2SZ + hr * 512 + (wq >> 1) * 32;
    const int S1X   = (4 * (wq & 1)) ^ ((wq >> 1) & 7) ^ hr;
    const int row   = hr + wid;            // staged x2 row 0..3

    int a2[12];                            // chunk-invariant x2 read addresses
    #pragma unroll
    for (int t = 0; t < 12; ++t) {
        const int sp = 4 * wq + t;         // padded pixel index 0..135
        a2[t] = row * 544 + (sp >> 3) * 32
              + (((sp & 7) ^ ((sp >> 3) & 7) ^ row) << 2);
    }

    float acc[4][9];
    #pragma unroll
    for (int p = 0; p < 4; ++p)
        #pragma unroll
        for (int d = 0; d < 9; ++d) acc[p][d] = 0.f;

    auto COMPUTE = [&](int j) {            // j = plane (literal at call site)
        const int jb = j * PL;
        uint4 x1v[4];
        #pragma unroll
        for (int p = 0; p < 4; ++p)
            x1v[p] = *reinterpret_cast<const uint4*>(
                &smem[jb + base1 + ((p ^ S1X) << 2)]);
        #pragma unroll
        for (int t = 0; t < 12; ++t) {
            const uint4 x2v = *reinterpret_cast<const uint4*>(&smem[jb + a2[t]]);
            #pragma unroll
            for (int p = 0; p < 4; ++p) {
                const int dxx = t - p;          // compile-time after unroll
                if (dxx >= 0 && dxx <= 8) {
                    float a = acc[p][dxx];
                    a = dot2(x1v[p].x, x2v.x, a);
                    a = dot2(x1v[p].y, x2v.y, a);
                    a = dot2(x1v[p].z, x2v.z, a);
                    a = dot2(x1v[p].w, x2v.w, a);
                    acc[p][dxx] = a;
                }
            }
        }
    };

    // ---------------- chunk loop: 2 planes per phase ------------------------
    // zero pad slots of both planes' s2 (g=0/33 quads, invalid rows)
    for (int i = tid; i < S2SZ; i += NTHR) { smem[i] = 0u; smem[PL + i] = 0u; }
    __syncthreads();

    #pragma unroll 1
    for (int cc = 0; cc < NCH; ++cc) {
        STAGE(cc, 0);
        STAGE(cc, 1);
        __syncthreads();
        COMPUTE(0);
        COMPUTE(1);
        __syncthreads();
    }

    // ---------------- epilogue: mean + leaky_relu + coalesced f32x4 writes -
    const float inv = 1.0f / 256.0f;
    const int dy = 3 * dg + wid;
    float* ob = out + (((size_t)(b * 81 + dy * 9)) * H_ + (h0 + hr)) * W_ + wq * 4;
    #pragma unroll
    for (int dxx = 0; dxx < 9; ++dxx) {
        float4 o;
        float v;
        v = acc[0][dxx] * inv; o.x = v >= 0.f ? v : 0.1f * v;
        v = acc[1][dxx] * inv; o.y = v >= 0.f ? v : 0.1f * v;
        v = acc[2][dxx] * inv; o.z = v >= 0.f ? v : 0.1f * v;
        v = acc[3][dxx] * inv; o.w = v >= 0.f ? v : 0.1f * v;
        *reinterpret_cast<float4*>(ob + (size_t)dxx * HW) = o;
    }
}

extern "C" void kernel_launch(void* const* d_in, const int* in_sizes, int n_in,
                              void* d_out, int out_size, void* d_ws, size_t ws_size,
                              hipStream_t stream) {
    const float* x1 = (const float*)d_in[0];
    const float* x2 = (const float*)d_in[1];
    float* out = (float*)d_out;
    corr_kernel<<<dim3(B_, H_ / TH, 3), dim3(NTHR), 0, stream>>>(x1, x2, out);
}